// Round 1
// baseline (220.664 us; speedup 1.0000x reference)
//
#include <hip/hip_runtime.h>
#include <hip/hip_bf16.h>
#include <math.h>

#define N_NODES 4096
#define DIN     512
#define DOUT    256
#define NH      3
#define BN_EPS  1e-5f

// ---------------------------------------------------------------------------
// K0: zero the BN stat accumulators (512 floats)
// ---------------------------------------------------------------------------
__global__ void k0_zero(float* __restrict__ sums) {
    if (threadIdx.x < 2 * DOUT) sums[threadIdx.x] = 0.0f;
}

// ---------------------------------------------------------------------------
// K1: proj[h][n][o] = sum_k features[n][k] * weight[h][k][o]   (fp32 GEMM)
// Block tile 64x64, BK=32, 256 threads, 4x4 micro-tile per thread.
// ---------------------------------------------------------------------------
#define BM 64
#define BN 64
#define BK 32

__global__ __launch_bounds__(256) void k1_proj(const float* __restrict__ F,
                                               const float* __restrict__ W,
                                               float* __restrict__ proj) {
    __shared__ float As[BK][72];   // transposed A tile, padded (72 = 64+8, keeps 16B align + spreads banks)
    __shared__ float Bs[BK][BN];
    const int h    = blockIdx.z;
    const int mblk = blockIdx.y;
    const int nblk = blockIdx.x;
    const int tid  = threadIdx.x;
    const int tx   = tid & 15;      // 16 col groups
    const int ty   = tid >> 4;      // 16 row groups
    const float* Fb = F + (size_t)mblk * BM * DIN;
    const float* Wb = W + (size_t)h * DIN * DOUT + nblk * BN;

    float acc[4][4] = {};

    for (int kb = 0; kb < DIN; kb += BK) {
        // ---- stage A (transposed into LDS) ----
        {
            const int r  = tid >> 3;          // 0..31
            const int kk = (tid & 7) << 2;    // 0..28
            #pragma unroll
            for (int p = 0; p < 2; ++p) {
                float4 v = *(const float4*)(Fb + (size_t)(r + 32 * p) * DIN + kb + kk);
                As[kk + 0][r + 32 * p] = v.x;
                As[kk + 1][r + 32 * p] = v.y;
                As[kk + 2][r + 32 * p] = v.z;
                As[kk + 3][r + 32 * p] = v.w;
            }
        }
        // ---- stage B ----
        {
            const int kr = tid >> 4;          // 0..15
            const int nn = (tid & 15) << 2;   // 0..60
            #pragma unroll
            for (int p = 0; p < 2; ++p) {
                float4 v = *(const float4*)(Wb + (size_t)(kb + kr + 16 * p) * DOUT + nn);
                *(float4*)&Bs[kr + 16 * p][nn] = v;
            }
        }
        __syncthreads();
        #pragma unroll
        for (int k = 0; k < BK; ++k) {
            float4 a4 = *(const float4*)&As[k][ty << 2];
            float4 b4 = *(const float4*)&Bs[k][tx << 2];
            float av[4] = {a4.x, a4.y, a4.z, a4.w};
            float bv[4] = {b4.x, b4.y, b4.z, b4.w};
            #pragma unroll
            for (int i = 0; i < 4; ++i)
                #pragma unroll
                for (int j = 0; j < 4; ++j)
                    acc[i][j] = fmaf(av[i], bv[j], acc[i][j]);
        }
        __syncthreads();
    }

    float* P = proj + (size_t)h * N_NODES * DOUT
                    + (size_t)(mblk * BM + (ty << 2)) * DOUT + nblk * BN + (tx << 2);
    #pragma unroll
    for (int i = 0; i < 4; ++i)
        *(float4*)(P + (size_t)i * DOUT) = make_float4(acc[i][0], acc[i][1], acc[i][2], acc[i][3]);
}

// ---------------------------------------------------------------------------
// K2: s_src[h][n] = proj[h][n][:] . score_src[h][:],  same for s_tgt
// One wave per row; 256-thread blocks = 4 rows/block.
// ---------------------------------------------------------------------------
__global__ __launch_bounds__(256) void k2_scores(const float* __restrict__ proj,
                                                 const float* __restrict__ ssw,
                                                 const float* __restrict__ stw,
                                                 float* __restrict__ s_src,
                                                 float* __restrict__ s_tgt) {
    const int wave = threadIdx.x >> 6;
    const int lane = threadIdx.x & 63;
    const int row  = blockIdx.x * 4 + wave;      // 0 .. 3*4096-1  (= h*4096+n)
    const int h    = row >> 12;

    const float* p = proj + (size_t)row * DOUT;
    float4 pv = *(const float4*)(p + lane * 4);
    float4 a  = *(const float4*)(ssw + h * DOUT + lane * 4);
    float4 b  = *(const float4*)(stw + h * DOUT + lane * 4);
    float ds = pv.x * a.x + pv.y * a.y + pv.z * a.z + pv.w * a.w;
    float dt = pv.x * b.x + pv.y * b.y + pv.z * b.z + pv.w * b.w;
    #pragma unroll
    for (int off = 32; off; off >>= 1) {
        ds += __shfl_down(ds, off);
        dt += __shfl_down(dt, off);
    }
    if (lane == 0) { s_src[row] = ds; s_tgt[row] = dt; }
}

// ---------------------------------------------------------------------------
// K3: per destination row i — compact nonzero adj entries (ballot), then for
// each head: softmax over edges (logit = leaky(s_src_i + s_tgt_j) + a_ij),
// accumulate att @ proj. Head-mean + bias written to out (pre-BN).
// One wave (64 threads) per row; lane owns output dims 4*lane..4*lane+3.
// ---------------------------------------------------------------------------
#define MAXE 512

__global__ __launch_bounds__(64) void k3_attn(const float* __restrict__ adj,
                                              const float* __restrict__ proj,
                                              const float* __restrict__ s_src,
                                              const float* __restrict__ s_tgt,
                                              const float* __restrict__ bias,
                                              float* __restrict__ outp) {
    __shared__ int   ej[MAXE];
    __shared__ float ea[MAXE];
    __shared__ float ep[MAXE];
    const int i    = blockIdx.x;
    const int lane = threadIdx.x;
    const float* arow = adj + (size_t)i * N_NODES;

    // ---- ballot compaction of nonzeros ----
    int cnt = 0;
    for (int c = lane; c < N_NODES; c += 64) {
        float a = arow[c];
        unsigned long long m = __ballot(a != 0.0f);
        if (a != 0.0f) {
            int pos = cnt + (int)__popcll(m & ((1ull << lane) - 1ull));
            if (pos < MAXE) { ej[pos] = c; ea[pos] = a; }
        }
        cnt += (int)__popcll(m);
    }
    if (cnt > MAXE) cnt = MAXE;   // statistically impossible (mean nnz ~41)
    __syncthreads();

    float4 acc = make_float4(0.f, 0.f, 0.f, 0.f);

    for (int h = 0; h < NH; ++h) {
        const float  ss = s_src[h * N_NODES + i];
        const float* st = s_tgt + h * N_NODES;
        const float* P  = proj + (size_t)h * N_NODES * DOUT;

        // pass 1: logits + row max
        float mx = -1e30f;
        for (int e = lane; e < cnt; e += 64) {
            float x  = ss + st[ej[e]];
            float lg = (x > 0.f ? x : 0.2f * x) + ea[e];
            ep[e] = lg;
            mx = fmaxf(mx, lg);
        }
        #pragma unroll
        for (int off = 32; off; off >>= 1) mx = fmaxf(mx, __shfl_xor(mx, off));

        // pass 2: exp + sum (same lane re-reads its own ep entries: no sync needed)
        float sum = 0.f;
        for (int e = lane; e < cnt; e += 64) {
            float p = __expf(ep[e] - mx);
            ep[e] = p;
            sum += p;
        }
        #pragma unroll
        for (int off = 32; off; off >>= 1) sum += __shfl_xor(sum, off);
        __syncthreads();                    // all ep visible to all lanes
        const float inv = 1.0f / sum;

        // pass 3: weighted gather-accumulate over edges
        float4 hacc = make_float4(0.f, 0.f, 0.f, 0.f);
        #pragma unroll 4
        for (int e = 0; e < cnt; ++e) {
            const float  p  = ep[e];
            const float4 pv = *(const float4*)(P + (size_t)ej[e] * DOUT + lane * 4);
            hacc.x = fmaf(p, pv.x, hacc.x);
            hacc.y = fmaf(p, pv.y, hacc.y);
            hacc.z = fmaf(p, pv.z, hacc.z);
            hacc.w = fmaf(p, pv.w, hacc.w);
        }
        acc.x += hacc.x * inv;
        acc.y += hacc.y * inv;
        acc.z += hacc.z * inv;
        acc.w += hacc.w * inv;
        __syncthreads();                    // before next head overwrites ep
    }

    const float4 bv = *(const float4*)(bias + lane * 4);
    const float s = 1.0f / (float)NH;
    float4 o = make_float4(acc.x * s + bv.x, acc.y * s + bv.y,
                           acc.z * s + bv.z, acc.w * s + bv.w);
    *(float4*)(outp + (size_t)i * DOUT + lane * 4) = o;
}

// ---------------------------------------------------------------------------
// K4: BN column stats — partial sums per 64-row slab, atomicAdd into sums[512]
// ---------------------------------------------------------------------------
__global__ __launch_bounds__(256) void k4_stats(const float* __restrict__ outp,
                                                float* __restrict__ sums) {
    const int t  = threadIdx.x;          // column
    const int r0 = blockIdx.x * 64;
    float s = 0.f, s2 = 0.f;
    for (int r = 0; r < 64; ++r) {
        float v = outp[(size_t)(r0 + r) * DOUT + t];
        s  += v;
        s2 += v * v;
    }
    atomicAdd(&sums[t], s);
    atomicAdd(&sums[DOUT + t], s2);
}

// ---------------------------------------------------------------------------
// K5: BN normalize (training-mode batch stats, biased var) + ReLU, in place
// ---------------------------------------------------------------------------
__global__ __launch_bounds__(256) void k5_bn(float* __restrict__ outp,
                                             const float* __restrict__ sums,
                                             const float* __restrict__ gamma,
                                             const float* __restrict__ beta) {
    const int idx = blockIdx.x * 256 + threadIdx.x;      // one float4 per thread
    float4 v = *(float4*)(outp + (size_t)idx * 4);
    const int c0 = (idx * 4) & (DOUT - 1);
    float vv[4] = {v.x, v.y, v.z, v.w};
    #pragma unroll
    for (int j = 0; j < 4; ++j) {
        const int c = c0 + j;
        float mu  = sums[c] * (1.0f / N_NODES);
        float var = sums[DOUT + c] * (1.0f / N_NODES) - mu * mu;
        float sc  = gamma[c] * rsqrtf(var + BN_EPS);
        float sh  = beta[c] - mu * sc;
        vv[j] = fmaxf(0.f, fmaf(vv[j], sc, sh));
    }
    *(float4*)(outp + (size_t)idx * 4) = make_float4(vv[0], vv[1], vv[2], vv[3]);
}

// ---------------------------------------------------------------------------
extern "C" void kernel_launch(void* const* d_in, const int* in_sizes, int n_in,
                              void* d_out, int out_size, void* d_ws, size_t ws_size,
                              hipStream_t stream) {
    const float* F     = (const float*)d_in[0];   // [4096,512]
    const float* A     = (const float*)d_in[1];   // [4096,4096]
    const float* W     = (const float*)d_in[2];   // [3,512,256]
    const float* bias  = (const float*)d_in[3];   // [256]
    const float* ssw   = (const float*)d_in[4];   // [3,256,1]
    const float* stw   = (const float*)d_in[5];   // [3,256,1]
    const float* gamma = (const float*)d_in[6];   // [256]
    const float* beta  = (const float*)d_in[7];   // [256]
    float* out = (float*)d_out;                   // [4096,256]

    float* proj  = (float*)d_ws;                          // 3*4096*256 fp32 = 12.58 MB
    float* s_src = proj  + (size_t)NH * N_NODES * DOUT;   // 3*4096
    float* s_tgt = s_src + NH * N_NODES;                  // 3*4096
    float* sums  = s_tgt + NH * N_NODES;                  // 512

    k0_zero<<<1, 512, 0, stream>>>(sums);
    k1_proj<<<dim3(DOUT / BN, N_NODES / BM, NH), 256, 0, stream>>>(F, W, proj);
    k2_scores<<<NH * N_NODES / 4, 256, 0, stream>>>(proj, ssw, stw, s_src, s_tgt);
    k3_attn<<<N_NODES, 64, 0, stream>>>(A, proj, s_src, s_tgt, bias, out);
    k4_stats<<<N_NODES / 64, 256, 0, stream>>>(out, sums);
    k5_bn<<<(size_t)N_NODES * DOUT / 4 / 256, 256, 0, stream>>>(out, sums, gamma, beta);
}

// Round 5
// 207.074 us; speedup vs baseline: 1.0656x; 1.0656x over previous
//
#include <hip/hip_runtime.h>
#include <hip/hip_bf16.h>
#include <math.h>

#define N_NODES 4096
#define DIN     512
#define DOUT    256
#define NH      3
#define BN_EPS  1e-5f
#define NPH     (N_NODES * DOUT)

typedef __attribute__((ext_vector_type(8))) short short8;
typedef __attribute__((ext_vector_type(4))) float f32x4;

// float -> bf16 bits (RNE) and back
__device__ __forceinline__ short f2bf(float x) {
    union { float f; unsigned u; } v; v.f = x;
    unsigned r = (v.u + 0x7FFFu + ((v.u >> 16) & 1u)) >> 16;
    return (short)r;
}
__device__ __forceinline__ float bf2f(short b) {
    union { float f; unsigned u; } v; v.u = ((unsigned)(unsigned short)b) << 16;
    return v.f;
}

// ---------------------------------------------------------------------------
// K0: zero the BN stat accumulators (512 floats)
// ---------------------------------------------------------------------------
__global__ void k0_zero(float* __restrict__ sums) {
    if (threadIdx.x < 2 * DOUT) sums[threadIdx.x] = 0.0f;
}

// ---------------------------------------------------------------------------
// K1w: W [3][512][256] f32  ->  W^T hi/lo bf16 [3][256][512]
// 64x64 LDS tile transpose per block.
// ---------------------------------------------------------------------------
__global__ __launch_bounds__(256) void k1w_split(const float* __restrict__ W,
                                                 short* __restrict__ WhiT,
                                                 short* __restrict__ WloT) {
    __shared__ float tile[64][72];           // padded, 16B-aligned rows
    const int h  = blockIdx.z;
    const int k0 = blockIdx.y * 64;
    const int n0 = blockIdx.x * 64;
    const int t  = threadIdx.x;

    // load: rows along k, coalesced float4 along n
    {
        const int col4 = (t & 15) * 4;
        #pragma unroll
        for (int p = 0; p < 4; ++p) {
            const int row = p * 16 + (t >> 4);
            float4 v = *(const float4*)(W + (size_t)h * DIN * DOUT + (size_t)(k0 + row) * DOUT + n0 + col4);
            *(float4*)&tile[row][col4] = v;
        }
    }
    __syncthreads();

    // transpose + split: thread owns one n-row, 16 consecutive k
    const int n  = t >> 2;
    const int kc = (t & 3) * 16;
    short hi[16], lo[16];
    #pragma unroll
    for (int i = 0; i < 16; ++i) {
        float x = tile[kc + i][n];
        short hb = f2bf(x);
        hi[i] = hb;
        lo[i] = f2bf(x - bf2f(hb));
    }
    short* oh = WhiT + ((size_t)h * DOUT + n0 + n) * DIN + k0 + kc;
    short* ol = WloT + ((size_t)h * DOUT + n0 + n) * DIN + k0 + kc;
    *(short8*)(oh)     = *(short8*)&hi[0];
    *(short8*)(oh + 8) = *(short8*)&hi[8];
    *(short8*)(ol)     = *(short8*)&lo[0];
    *(short8*)(ol + 8) = *(short8*)&lo[8];
}

// ---------------------------------------------------------------------------
// K1: proj[h][n][o] = F @ W[h]  via bf16x3 split MFMA (fp32-class accuracy).
// Block tile 128(M) x 64(N), BK=32, 256 threads (4 waves, each 64x32).
// F converted to hi/lo bf16 on the fly during staging.
// LDS rows padded to 40 shorts (80 B = 20 banks): fragment ds_read_b128 at
// 64 B stride would be 8-way bank-conflicted; 80 B stride cycles banks with
// period 8 -> 2-way aliasing (free per m136).
// MFMA 16x16x32_bf16 layouts (m89/m91-verified convention):
//   A: row = lane&15, k = 8*(lane>>4)+j     B: col = lane&15, same k
//   D: col = lane&15, row = 4*(lane>>4)+reg
// ---------------------------------------------------------------------------
#define APAD 40

__global__ __launch_bounds__(256) void k1_proj(const float* __restrict__ F,
                                               const short* __restrict__ WhiT,
                                               const short* __restrict__ WloT,
                                               float* __restrict__ proj) {
    __shared__ short Ahi[128][APAD], Alo[128][APAD];
    __shared__ short Bhi[64][APAD],  Blo[64][APAD];

    const int h    = blockIdx.z;
    const int mblk = blockIdx.y;
    const int nblk = blockIdx.x;
    const int t    = threadIdx.x;
    const int wid  = t >> 6;
    const int l    = t & 63;
    const int wm   = wid >> 1;          // 0..1  (64-row half)
    const int wn   = wid & 1;           // 0..1  (32-col half)
    const int lr   = l & 15;
    const int lk8  = (l >> 4) * 8;

    // staging coords
    const int arow  = t >> 1;           // 0..127
    const int ahalf = (t & 1) * 16;     // 0 / 16
    const int bn    = t >> 2;           // 0..63
    const int bkc   = (t & 3) * 8;      // 0..24

    const float* Fb  = F + (size_t)(mblk * 128 + arow) * DIN + ahalf;
    const short* WhB = WhiT + ((size_t)h * DOUT + nblk * 64 + bn) * DIN + bkc;
    const short* WlB = WloT + ((size_t)h * DOUT + nblk * 64 + bn) * DIN + bkc;

    f32x4 acc[4][2];
    #pragma unroll
    for (int mf = 0; mf < 4; ++mf)
        #pragma unroll
        for (int nf = 0; nf < 2; ++nf)
            acc[mf][nf] = (f32x4){0.f, 0.f, 0.f, 0.f};

    for (int kb = 0; kb < DIN; kb += 32) {
        // ---- stage A: 16 floats/thread, convert to hi/lo bf16 ----
        {
            short hi[16], lo[16];
            #pragma unroll
            for (int q = 0; q < 4; ++q) {
                float4 v = *(const float4*)(Fb + kb + q * 4);
                float xs[4] = {v.x, v.y, v.z, v.w};
                #pragma unroll
                for (int j = 0; j < 4; ++j) {
                    short hb = f2bf(xs[j]);
                    hi[q * 4 + j] = hb;
                    lo[q * 4 + j] = f2bf(xs[j] - bf2f(hb));
                }
            }
            *(short8*)&Ahi[arow][ahalf]     = *(short8*)&hi[0];
            *(short8*)&Ahi[arow][ahalf + 8] = *(short8*)&hi[8];
            *(short8*)&Alo[arow][ahalf]     = *(short8*)&lo[0];
            *(short8*)&Alo[arow][ahalf + 8] = *(short8*)&lo[8];
        }
        // ---- stage B: pre-split bf16, straight copy ----
        *(short8*)&Bhi[bn][bkc] = *(const short8*)(WhB + kb);
        *(short8*)&Blo[bn][bkc] = *(const short8*)(WlB + kb);
        __syncthreads();

        // ---- fragments ----
        short8 ah[4], al[4], bh[2], bl[2];
        #pragma unroll
        for (int mf = 0; mf < 4; ++mf) {
            ah[mf] = *(const short8*)&Ahi[wm * 64 + mf * 16 + lr][lk8];
            al[mf] = *(const short8*)&Alo[wm * 64 + mf * 16 + lr][lk8];
        }
        #pragma unroll
        for (int nf = 0; nf < 2; ++nf) {
            bh[nf] = *(const short8*)&Bhi[wn * 32 + nf * 16 + lr][lk8];
            bl[nf] = *(const short8*)&Blo[wn * 32 + nf * 16 + lr][lk8];
        }
        #pragma unroll
        for (int mf = 0; mf < 4; ++mf)
            #pragma unroll
            for (int nf = 0; nf < 2; ++nf) {
                acc[mf][nf] = __builtin_amdgcn_mfma_f32_16x16x32_bf16(ah[mf], bh[nf], acc[mf][nf], 0, 0, 0);
                acc[mf][nf] = __builtin_amdgcn_mfma_f32_16x16x32_bf16(ah[mf], bl[nf], acc[mf][nf], 0, 0, 0);
                acc[mf][nf] = __builtin_amdgcn_mfma_f32_16x16x32_bf16(al[mf], bh[nf], acc[mf][nf], 0, 0, 0);
            }
        __syncthreads();
    }

    // ---- epilogue: D col=lane&15, row=4*(lane>>4)+reg ----
    float* P = proj + (size_t)h * NPH
             + (size_t)(mblk * 128 + wm * 64) * DOUT + nblk * 64 + wn * 32;
    #pragma unroll
    for (int mf = 0; mf < 4; ++mf)
        #pragma unroll
        for (int nf = 0; nf < 2; ++nf)
            #pragma unroll
            for (int r = 0; r < 4; ++r)
                P[(size_t)(mf * 16 + (l >> 4) * 4 + r) * DOUT + nf * 16 + lr] = acc[mf][nf][r];
}

// ---------------------------------------------------------------------------
// K2: s_src[h][n] = proj[h][n][:] . score_src[h][:],  same for s_tgt
// ---------------------------------------------------------------------------
__global__ __launch_bounds__(256) void k2_scores(const float* __restrict__ proj,
                                                 const float* __restrict__ ssw,
                                                 const float* __restrict__ stw,
                                                 float* __restrict__ s_src,
                                                 float* __restrict__ s_tgt) {
    const int wave = threadIdx.x >> 6;
    const int lane = threadIdx.x & 63;
    const int row  = blockIdx.x * 4 + wave;      // 0 .. 3*4096-1  (= h*4096+n)
    const int h    = row >> 12;

    const float* p = proj + (size_t)row * DOUT;
    float4 pv = *(const float4*)(p + lane * 4);
    float4 a  = *(const float4*)(ssw + h * DOUT + lane * 4);
    float4 b  = *(const float4*)(stw + h * DOUT + lane * 4);
    float ds = pv.x * a.x + pv.y * a.y + pv.z * a.z + pv.w * a.w;
    float dt = pv.x * b.x + pv.y * b.y + pv.z * b.z + pv.w * b.w;
    #pragma unroll
    for (int off = 32; off; off >>= 1) {
        ds += __shfl_down(ds, off);
        dt += __shfl_down(dt, off);
    }
    if (lane == 0) { s_src[row] = ds; s_tgt[row] = dt; }
}

// ---------------------------------------------------------------------------
// K3: per destination row i — 256 threads (4 waves). Per-wave ballot
// compaction of a 1024-col quarter; block-wide softmax; head-interleaved
// coalesced gather-accumulate (thread owns one output dim).
// ---------------------------------------------------------------------------
#define SEG 128

__global__ __launch_bounds__(256) void k3_attn(const float* __restrict__ adj,
                                               const float* __restrict__ proj,
                                               const float* __restrict__ s_src,
                                               const float* __restrict__ s_tgt,
                                               const float* __restrict__ bias,
                                               float* __restrict__ outp) {
    __shared__ int   ej[4][SEG];
    __shared__ float ea[4][SEG];
    __shared__ float ep[NH][4][SEG];
    __shared__ int   cntw[4];
    __shared__ float red[8];

    const int i    = blockIdx.x;
    const int tid  = threadIdx.x;
    const int w    = tid >> 6;
    const int lane = tid & 63;
    const float* arow = adj + (size_t)i * N_NODES + w * 1024;

    // ---- per-wave ballot compaction of one quarter of the row ----
    int cnt = 0;
    for (int c0 = lane; c0 < 1024; c0 += 64) {
        float a = arow[c0];
        unsigned long long m = __ballot(a != 0.0f);
        if (a != 0.0f) {
            int pos = cnt + (int)__popcll(m & ((1ull << lane) - 1ull));
            if (pos < SEG) { ej[w][pos] = w * 1024 + c0; ea[w][pos] = a; }
        }
        cnt += (int)__popcll(m);
    }
    if (lane == 0) cntw[w] = (cnt > SEG ? SEG : cnt);
    __syncthreads();

    float inv[NH];

    // ---- per-head softmax over compacted edges (block-wide) ----
    #pragma unroll
    for (int h = 0; h < NH; ++h) {
        const float  ss = s_src[h * N_NODES + i];
        const float* st = s_tgt + h * N_NODES;

        float mx = -1e30f;
        #pragma unroll
        for (int seg = 0; seg < 4; ++seg) {
            const int n = cntw[seg];
            for (int e = tid; e < n; e += 256) {
                float x  = ss + st[ej[seg][e]];
                float lg = (x > 0.f ? x : 0.2f * x) + ea[seg][e];
                ep[h][seg][e] = lg;
                mx = fmaxf(mx, lg);
            }
        }
        #pragma unroll
        for (int off = 32; off; off >>= 1) mx = fmaxf(mx, __shfl_xor(mx, off));
        if (lane == 0) red[w] = mx;
        __syncthreads();
        mx = fmaxf(fmaxf(red[0], red[1]), fmaxf(red[2], red[3]));

        float sum = 0.f;
        #pragma unroll
        for (int seg = 0; seg < 4; ++seg) {
            const int n = cntw[seg];
            for (int e = tid; e < n; e += 256) {
                float p = __expf(ep[h][seg][e] - mx);
                ep[h][seg][e] = p;
                sum += p;
            }
        }
        #pragma unroll
        for (int off = 32; off; off >>= 1) sum += __shfl_xor(sum, off);
        if (lane == 0) red[4 + w] = sum;
        __syncthreads();
        inv[h] = 1.0f / (red[4] + red[5] + red[6] + red[7]);
    }

    // ---- gather-accumulate: thread owns output dim `tid`, heads interleaved
    const int d = tid;
    float a0 = 0.f, a1 = 0.f, a2 = 0.f;
    #pragma unroll
    for (int seg = 0; seg < 4; ++seg) {
        const int n = cntw[seg];
        #pragma unroll 4
        for (int e = 0; e < n; ++e) {
            const size_t col = (size_t)ej[seg][e] * DOUT + d;
            const float p0 = ep[0][seg][e];
            const float p1 = ep[1][seg][e];
            const float p2 = ep[2][seg][e];
            a0 = fmaf(p0, proj[col], a0);
            a1 = fmaf(p1, proj[NPH + col], a1);
            a2 = fmaf(p2, proj[2 * NPH + col], a2);
        }
    }

    const float o = (a0 * inv[0] + a1 * inv[1] + a2 * inv[2]) * (1.0f / NH) + bias[d];
    outp[(size_t)i * DOUT + d] = o;
}

// ---------------------------------------------------------------------------
// K4: BN column stats — partial sums per 64-row slab, atomicAdd into sums[512]
// ---------------------------------------------------------------------------
__global__ __launch_bounds__(256) void k4_stats(const float* __restrict__ outp,
                                                float* __restrict__ sums) {
    const int t  = threadIdx.x;          // column
    const int r0 = blockIdx.x * 64;
    float s = 0.f, s2 = 0.f;
    for (int r = 0; r < 64; ++r) {
        float v = outp[(size_t)(r0 + r) * DOUT + t];
        s  += v;
        s2 += v * v;
    }
    atomicAdd(&sums[t], s);
    atomicAdd(&sums[DOUT + t], s2);
}

// ---------------------------------------------------------------------------
// K5: BN normalize (training-mode batch stats, biased var) + ReLU, in place
// ---------------------------------------------------------------------------
__global__ __launch_bounds__(256) void k5_bn(float* __restrict__ outp,
                                             const float* __restrict__ sums,
                                             const float* __restrict__ gamma,
                                             const float* __restrict__ beta) {
    const int idx = blockIdx.x * 256 + threadIdx.x;      // one float4 per thread
    float4 v = *(float4*)(outp + (size_t)idx * 4);
    const int c0 = (idx * 4) & (DOUT - 1);
    float vv[4] = {v.x, v.y, v.z, v.w};
    #pragma unroll
    for (int j = 0; j < 4; ++j) {
        const int c = c0 + j;
        float mu  = sums[c] * (1.0f / N_NODES);
        float var = sums[DOUT + c] * (1.0f / N_NODES) - mu * mu;
        float sc  = gamma[c] * rsqrtf(var + BN_EPS);
        float sh  = beta[c] - mu * sc;
        vv[j] = fmaxf(0.f, fmaf(vv[j], sc, sh));
    }
    *(float4*)(outp + (size_t)idx * 4) = make_float4(vv[0], vv[1], vv[2], vv[3]);
}

// ---------------------------------------------------------------------------
extern "C" void kernel_launch(void* const* d_in, const int* in_sizes, int n_in,
                              void* d_out, int out_size, void* d_ws, size_t ws_size,
                              hipStream_t stream) {
    const float* F     = (const float*)d_in[0];   // [4096,512]
    const float* A     = (const float*)d_in[1];   // [4096,4096]
    const float* W     = (const float*)d_in[2];   // [3,512,256]
    const float* bias  = (const float*)d_in[3];   // [256]
    const float* ssw   = (const float*)d_in[4];   // [3,256,1]
    const float* stw   = (const float*)d_in[5];   // [3,256,1]
    const float* gamma = (const float*)d_in[6];   // [256]
    const float* beta  = (const float*)d_in[7];   // [256]
    float* out = (float*)d_out;                   // [4096,256]

    float* proj  = (float*)d_ws;                          // 3*4096*256 fp32 = 12.58 MB
    float* s_src = proj  + (size_t)NH * N_NODES * DOUT;   // 3*4096
    float* s_tgt = s_src + NH * N_NODES;                  // 3*4096
    float* sums  = s_tgt + NH * N_NODES;                  // 512
    short* WhiT  = (short*)(sums + 2 * DOUT);             // 3*256*512 bf16 = 0.75 MB
    short* WloT  = WhiT + (size_t)NH * DOUT * DIN;        // 0.75 MB

    k0_zero<<<1, 512, 0, stream>>>(sums);
    k1w_split<<<dim3(DOUT / 64, DIN / 64, NH), 256, 0, stream>>>(W, WhiT, WloT);
    k1_proj<<<dim3(DOUT / 64, N_NODES / 128, NH), 256, 0, stream>>>(F, WhiT, WloT, proj);
    k2_scores<<<NH * N_NODES / 4, 256, 0, stream>>>(proj, ssw, stw, s_src, s_tgt);
    k3_attn<<<N_NODES, 256, 0, stream>>>(A, proj, s_src, s_tgt, bias, out);
    k4_stats<<<N_NODES / 64, 256, 0, stream>>>(out, sums);
    k5_bn<<<(size_t)N_NODES * DOUT / 4 / 256, 256, 0, stream>>>(out, sums, gamma, beta);
}

// Round 6
// 195.847 us; speedup vs baseline: 1.1267x; 1.0573x over previous
//
#include <hip/hip_runtime.h>
#include <hip/hip_bf16.h>
#include <math.h>

#define N_NODES 4096
#define DIN     512
#define DOUT    256
#define NH      3
#define BN_EPS  1e-5f
#define NPH     (N_NODES * DOUT)

typedef __attribute__((ext_vector_type(8))) short short8;
typedef __attribute__((ext_vector_type(4))) float f32x4;

// float -> bf16 bits (RNE) and back
__device__ __forceinline__ short f2bf(float x) {
    union { float f; unsigned u; } v; v.f = x;
    unsigned r = (v.u + 0x7FFFu + ((v.u >> 16) & 1u)) >> 16;
    return (short)r;
}
__device__ __forceinline__ float bf2f(short b) {
    union { float f; unsigned u; } v; v.u = ((unsigned)(unsigned short)b) << 16;
    return v.f;
}

// ---------------------------------------------------------------------------
// K1f: F [4096][512] f32 -> Fhi/Flo bf16 (row-major), split ONCE (was 12x
// redundant on-the-fly convert inside k1's K-loop).
// ---------------------------------------------------------------------------
__global__ __launch_bounds__(256) void k1f_split(const float* __restrict__ F,
                                                 short* __restrict__ Fhi,
                                                 short* __restrict__ Flo) {
    const size_t base = ((size_t)blockIdx.x * 256 + threadIdx.x) * 8;
    float4 v0 = *(const float4*)(F + base);
    float4 v1 = *(const float4*)(F + base + 4);
    float xs[8] = {v0.x, v0.y, v0.z, v0.w, v1.x, v1.y, v1.z, v1.w};
    short hi[8], lo[8];
    #pragma unroll
    for (int j = 0; j < 8; ++j) {
        short hb = f2bf(xs[j]);
        hi[j] = hb;
        lo[j] = f2bf(xs[j] - bf2f(hb));
    }
    *(short8*)(Fhi + base) = *(short8*)hi;
    *(short8*)(Flo + base) = *(short8*)lo;
}

// ---------------------------------------------------------------------------
// K1w: W [3][512][256] f32 -> W^T hi/lo bf16 [3][256][512]
// ---------------------------------------------------------------------------
__global__ __launch_bounds__(256) void k1w_split(const float* __restrict__ W,
                                                 short* __restrict__ WhiT,
                                                 short* __restrict__ WloT) {
    __shared__ float tile[64][72];
    const int h  = blockIdx.z;
    const int k0 = blockIdx.y * 64;
    const int n0 = blockIdx.x * 64;
    const int t  = threadIdx.x;
    {
        const int col4 = (t & 15) * 4;
        #pragma unroll
        for (int p = 0; p < 4; ++p) {
            const int row = p * 16 + (t >> 4);
            float4 v = *(const float4*)(W + (size_t)h * DIN * DOUT + (size_t)(k0 + row) * DOUT + n0 + col4);
            *(float4*)&tile[row][col4] = v;
        }
    }
    __syncthreads();
    const int n  = t >> 2;
    const int kc = (t & 3) * 16;
    short hi[16], lo[16];
    #pragma unroll
    for (int i = 0; i < 16; ++i) {
        float x = tile[kc + i][n];
        short hb = f2bf(x);
        hi[i] = hb;
        lo[i] = f2bf(x - bf2f(hb));
    }
    short* oh = WhiT + ((size_t)h * DOUT + n0 + n) * DIN + k0 + kc;
    short* ol = WloT + ((size_t)h * DOUT + n0 + n) * DIN + k0 + kc;
    *(short8*)(oh)     = *(short8*)&hi[0];
    *(short8*)(oh + 8) = *(short8*)&hi[8];
    *(short8*)(ol)     = *(short8*)&lo[0];
    *(short8*)(ol + 8) = *(short8*)&lo[8];
}

// ---------------------------------------------------------------------------
// K1: proj[h] = F @ W[h] via bf16x3 split MFMA; pure copy staging (inputs
// pre-split). Fused k2 epilogue: s_src/s_tgt partial dot per 16-lane group,
// shfl-reduced, atomicAdd (buffers pre-zeroed by memset).
// Tile 128(M)x64(N), BK=32, 4 waves each 64x32. LDS rows padded to 40 shorts
// (80 B): b128 frag reads cycle banks period 8 -> 2-way aliasing (free).
// MFMA 16x16x32_bf16: A row=lane&15, k=8*(lane>>4)+j; B col=lane&15;
// D col=lane&15, row=4*(lane>>4)+reg.
// ---------------------------------------------------------------------------
#define APAD 40

__global__ __launch_bounds__(256) void k1_proj(const short* __restrict__ Fhi,
                                               const short* __restrict__ Flo,
                                               const short* __restrict__ WhiT,
                                               const short* __restrict__ WloT,
                                               const float* __restrict__ ssw,
                                               const float* __restrict__ stw,
                                               float* __restrict__ proj,
                                               float* __restrict__ s_src,
                                               float* __restrict__ s_tgt) {
    __shared__ short Ahi[128][APAD], Alo[128][APAD];
    __shared__ short Bhi[64][APAD],  Blo[64][APAD];

    const int h    = blockIdx.z;
    const int mblk = blockIdx.y;
    const int nblk = blockIdx.x;
    const int t    = threadIdx.x;
    const int wid  = t >> 6;
    const int l    = t & 63;
    const int wm   = wid >> 1;
    const int wn   = wid & 1;
    const int lr   = l & 15;
    const int lk8  = (l >> 4) * 8;

    const int arow  = t >> 1;           // 0..127
    const int ahalf = (t & 1) * 16;     // 0 / 16
    const int bn    = t >> 2;           // 0..63
    const int bkc   = (t & 3) * 8;      // 0..24

    const short* FhB = Fhi + (size_t)(mblk * 128 + arow) * DIN + ahalf;
    const short* FlB = Flo + (size_t)(mblk * 128 + arow) * DIN + ahalf;
    const short* WhB = WhiT + ((size_t)h * DOUT + nblk * 64 + bn) * DIN + bkc;
    const short* WlB = WloT + ((size_t)h * DOUT + nblk * 64 + bn) * DIN + bkc;

    f32x4 acc[4][2];
    #pragma unroll
    for (int mf = 0; mf < 4; ++mf)
        #pragma unroll
        for (int nf = 0; nf < 2; ++nf)
            acc[mf][nf] = (f32x4){0.f, 0.f, 0.f, 0.f};

    for (int kb = 0; kb < DIN; kb += 32) {
        *(short8*)&Ahi[arow][ahalf]     = *(const short8*)(FhB + kb);
        *(short8*)&Ahi[arow][ahalf + 8] = *(const short8*)(FhB + kb + 8);
        *(short8*)&Alo[arow][ahalf]     = *(const short8*)(FlB + kb);
        *(short8*)&Alo[arow][ahalf + 8] = *(const short8*)(FlB + kb + 8);
        *(short8*)&Bhi[bn][bkc] = *(const short8*)(WhB + kb);
        *(short8*)&Blo[bn][bkc] = *(const short8*)(WlB + kb);
        __syncthreads();

        short8 ah[4], al[4], bh[2], bl[2];
        #pragma unroll
        for (int mf = 0; mf < 4; ++mf) {
            ah[mf] = *(const short8*)&Ahi[wm * 64 + mf * 16 + lr][lk8];
            al[mf] = *(const short8*)&Alo[wm * 64 + mf * 16 + lr][lk8];
        }
        #pragma unroll
        for (int nf = 0; nf < 2; ++nf) {
            bh[nf] = *(const short8*)&Bhi[wn * 32 + nf * 16 + lr][lk8];
            bl[nf] = *(const short8*)&Blo[wn * 32 + nf * 16 + lr][lk8];
        }
        #pragma unroll
        for (int mf = 0; mf < 4; ++mf)
            #pragma unroll
            for (int nf = 0; nf < 2; ++nf) {
                acc[mf][nf] = __builtin_amdgcn_mfma_f32_16x16x32_bf16(ah[mf], bh[nf], acc[mf][nf], 0, 0, 0);
                acc[mf][nf] = __builtin_amdgcn_mfma_f32_16x16x32_bf16(ah[mf], bl[nf], acc[mf][nf], 0, 0, 0);
                acc[mf][nf] = __builtin_amdgcn_mfma_f32_16x16x32_bf16(al[mf], bh[nf], acc[mf][nf], 0, 0, 0);
            }
        __syncthreads();
    }

    // ---- write proj ----
    float* P = proj + (size_t)h * NPH
             + (size_t)(mblk * 128 + wm * 64) * DOUT + nblk * 64 + wn * 32;
    #pragma unroll
    for (int mf = 0; mf < 4; ++mf)
        #pragma unroll
        for (int nf = 0; nf < 2; ++nf)
            #pragma unroll
            for (int r = 0; r < 4; ++r)
                P[(size_t)(mf * 16 + (l >> 4) * 4 + r) * DOUT + nf * 16 + lr] = acc[mf][nf][r];

    // ---- fused k2: s_src/s_tgt partial dots ----
    const int c0 = nblk * 64 + wn * 32 + lr;        // nf=0 col
    const int c1 = c0 + 16;                          // nf=1 col
    const float sA0 = ssw[h * DOUT + c0], sA1 = ssw[h * DOUT + c1];
    const float sB0 = stw[h * DOUT + c0], sB1 = stw[h * DOUT + c1];
    #pragma unroll
    for (int mf = 0; mf < 4; ++mf)
        #pragma unroll
        for (int r = 0; r < 4; ++r) {
            float ps = acc[mf][0][r] * sA0 + acc[mf][1][r] * sA1;
            float pt = acc[mf][0][r] * sB0 + acc[mf][1][r] * sB1;
            #pragma unroll
            for (int off = 1; off < 16; off <<= 1) {
                ps += __shfl_xor(ps, off);
                pt += __shfl_xor(pt, off);
            }
            if (lr == 0) {
                const int row = mblk * 128 + wm * 64 + mf * 16 + (l >> 4) * 4 + r;
                atomicAdd(&s_src[h * N_NODES + row], ps);
                atomicAdd(&s_tgt[h * N_NODES + row], pt);
            }
        }
}

// ---------------------------------------------------------------------------
// K3: 4 rows per 256-thread block, one wave per row. Wave w compacts quarter
// w of all 4 rows (row-interleaved ballot chains, ILP 4); ONE barrier; then
// per-wave softmax fully in registers (cnt<=40/seg < 64 lanes: no loops, no
// block reductions) and float4 gather (lane owns 4 dims, 3 heads interleaved
// -> 12 x 16B loads in flight per lane).
// ---------------------------------------------------------------------------
#define SEGC 40
#define ROWE (4 * SEGC)

__global__ __launch_bounds__(256) void k3_attn(const float* __restrict__ adj,
                                               const float* __restrict__ proj,
                                               const float* __restrict__ s_src,
                                               const float* __restrict__ s_tgt,
                                               const float* __restrict__ bias,
                                               float* __restrict__ outp) {
    __shared__ int   ej[4][ROWE];
    __shared__ float ea[4][ROWE];
    __shared__ float ep[NH][4][ROWE];
    __shared__ int   cnts[4][4];     // [row][seg]

    const int r0   = blockIdx.x * 4;
    const int t    = threadIdx.x;
    const int w    = t >> 6;
    const int lane = t & 63;
    const unsigned long long ltmask = (lane == 63) ? 0x7FFFFFFFFFFFFFFFull
                                                   : ((1ull << lane) - 1ull);

    // ---- phase A: wave w compacts cols [w*1024, w*1024+1024) of rows r0..r0+3
    int cnt[4] = {0, 0, 0, 0};
    for (int it = 0; it < 16; ++it) {
        const int c = w * 1024 + it * 64 + lane;
        float av[4];
        #pragma unroll
        for (int r = 0; r < 4; ++r)
            av[r] = adj[(size_t)(r0 + r) * N_NODES + c];
        #pragma unroll
        for (int r = 0; r < 4; ++r) {
            unsigned long long m = __ballot(av[r] != 0.0f);
            if (av[r] != 0.0f) {
                int pos = cnt[r] + (int)__popcll(m & ltmask);
                if (pos < SEGC) { ej[r][w * SEGC + pos] = c; ea[r][w * SEGC + pos] = av[r]; }
            }
            cnt[r] += (int)__popcll(m);
        }
    }
    if (lane == 0) {
        #pragma unroll
        for (int r = 0; r < 4; ++r)
            cnts[r][w] = (cnt[r] > SEGC ? SEGC : cnt[r]);
    }
    __syncthreads();

    // ---- from here: wave w owns row r0+w; everything wave-local ----
    const int row = r0 + w;
    int n[4], jj[4];
    float aa[4];
    #pragma unroll
    for (int s = 0; s < 4; ++s) {
        n[s] = cnts[w][s];
        if (lane < n[s]) { jj[s] = ej[w][s * SEGC + lane]; aa[s] = ea[w][s * SEGC + lane]; }
        else             { jj[s] = 0; aa[s] = 0.f; }
    }

    float inv[NH];
    #pragma unroll
    for (int h = 0; h < NH; ++h) {
        const float  ss = s_src[h * N_NODES + row];
        const float* st = s_tgt + h * N_NODES;
        float lg[4];
        #pragma unroll
        for (int s = 0; s < 4; ++s) {
            if (lane < n[s]) {
                float x = ss + st[jj[s]];
                lg[s] = (x > 0.f ? x : 0.2f * x) + aa[s];
            } else lg[s] = -1e30f;
        }
        float mx = fmaxf(fmaxf(lg[0], lg[1]), fmaxf(lg[2], lg[3]));
        #pragma unroll
        for (int off = 32; off; off >>= 1) mx = fmaxf(mx, __shfl_xor(mx, off));
        float ps[4], sum = 0.f;
        #pragma unroll
        for (int s = 0; s < 4; ++s) { ps[s] = __expf(lg[s] - mx); sum += ps[s]; }
        #pragma unroll
        for (int off = 32; off; off >>= 1) sum += __shfl_xor(sum, off);
        #pragma unroll
        for (int s = 0; s < 4; ++s)
            if (lane < n[s]) ep[h][w][s * SEGC + lane] = ps[s];
        inv[h] = 1.0f / sum;
    }

    // ---- phase C: float4 gather, 3 heads interleaved; lane owns dims 4l..4l+3
    const int d0 = lane * 4;
    float4 a0 = make_float4(0.f, 0.f, 0.f, 0.f);
    float4 a1 = a0, a2 = a0;
    #pragma unroll
    for (int s = 0; s < 4; ++s) {
        const int ns = n[s];
        #pragma unroll 4
        for (int e = 0; e < ns; ++e) {
            const int   j  = ej[w][s * SEGC + e];          // LDS broadcast
            const float p0 = ep[0][w][s * SEGC + e];
            const float p1 = ep[1][w][s * SEGC + e];
            const float p2 = ep[2][w][s * SEGC + e];
            const float* pb = proj + (size_t)j * DOUT + d0;
            float4 v0 = *(const float4*)pb;
            float4 v1 = *(const float4*)(pb + NPH);
            float4 v2 = *(const float4*)(pb + 2 * NPH);
            a0.x = fmaf(p0, v0.x, a0.x); a0.y = fmaf(p0, v0.y, a0.y);
            a0.z = fmaf(p0, v0.z, a0.z); a0.w = fmaf(p0, v0.w, a0.w);
            a1.x = fmaf(p1, v1.x, a1.x); a1.y = fmaf(p1, v1.y, a1.y);
            a1.z = fmaf(p1, v1.z, a1.z); a1.w = fmaf(p1, v1.w, a1.w);
            a2.x = fmaf(p2, v2.x, a2.x); a2.y = fmaf(p2, v2.y, a2.y);
            a2.z = fmaf(p2, v2.z, a2.z); a2.w = fmaf(p2, v2.w, a2.w);
        }
    }
    const float s3 = 1.0f / (float)NH;
    const float4 bv = *(const float4*)(bias + d0);
    float4 o;
    o.x = (a0.x * inv[0] + a1.x * inv[1] + a2.x * inv[2]) * s3 + bv.x;
    o.y = (a0.y * inv[0] + a1.y * inv[1] + a2.y * inv[2]) * s3 + bv.y;
    o.z = (a0.z * inv[0] + a1.z * inv[1] + a2.z * inv[2]) * s3 + bv.z;
    o.w = (a0.w * inv[0] + a1.w * inv[1] + a2.w * inv[2]) * s3 + bv.w;
    *(float4*)(outp + (size_t)row * DOUT + d0) = o;
}

// ---------------------------------------------------------------------------
// K4: BN column stats — partial sums per 64-row slab, atomicAdd into sums[512]
// ---------------------------------------------------------------------------
__global__ __launch_bounds__(256) void k4_stats(const float* __restrict__ outp,
                                                float* __restrict__ sums) {
    const int t  = threadIdx.x;
    const int r0 = blockIdx.x * 64;
    float s = 0.f, s2 = 0.f;
    for (int r = 0; r < 64; ++r) {
        float v = outp[(size_t)(r0 + r) * DOUT + t];
        s  += v;
        s2 += v * v;
    }
    atomicAdd(&sums[t], s);
    atomicAdd(&sums[DOUT + t], s2);
}

// ---------------------------------------------------------------------------
// K5: BN normalize (batch stats, biased var) + ReLU, in place
// ---------------------------------------------------------------------------
__global__ __launch_bounds__(256) void k5_bn(float* __restrict__ outp,
                                             const float* __restrict__ sums,
                                             const float* __restrict__ gamma,
                                             const float* __restrict__ beta) {
    const int idx = blockIdx.x * 256 + threadIdx.x;
    float4 v = *(float4*)(outp + (size_t)idx * 4);
    const int c0 = (idx * 4) & (DOUT - 1);
    float vv[4] = {v.x, v.y, v.z, v.w};
    #pragma unroll
    for (int j = 0; j < 4; ++j) {
        const int c = c0 + j;
        float mu  = sums[c] * (1.0f / N_NODES);
        float var = sums[DOUT + c] * (1.0f / N_NODES) - mu * mu;
        float sc  = gamma[c] * rsqrtf(var + BN_EPS);
        float sh  = beta[c] - mu * sc;
        vv[j] = fmaxf(0.f, fmaf(vv[j], sc, sh));
    }
    *(float4*)(outp + (size_t)idx * 4) = make_float4(vv[0], vv[1], vv[2], vv[3]);
}

// ---------------------------------------------------------------------------
extern "C" void kernel_launch(void* const* d_in, const int* in_sizes, int n_in,
                              void* d_out, int out_size, void* d_ws, size_t ws_size,
                              hipStream_t stream) {
    const float* F     = (const float*)d_in[0];   // [4096,512]
    const float* A     = (const float*)d_in[1];   // [4096,4096]
    const float* W     = (const float*)d_in[2];   // [3,512,256]
    const float* bias  = (const float*)d_in[3];   // [256]
    const float* ssw   = (const float*)d_in[4];   // [3,256,1]
    const float* stw   = (const float*)d_in[5];   // [3,256,1]
    const float* gamma = (const float*)d_in[6];   // [256]
    const float* beta  = (const float*)d_in[7];   // [256]
    float* out = (float*)d_out;                   // [4096,256]

    float* proj  = (float*)d_ws;                          // 12.58 MB
    float* s_src = proj  + (size_t)NH * N_NODES * DOUT;   // 3*4096
    float* s_tgt = s_src + NH * N_NODES;                  // 3*4096
    float* sums  = s_tgt + NH * N_NODES;                  // 512
    short* WhiT  = (short*)(sums + 2 * DOUT);             // 0.75 MB
    short* WloT  = WhiT + (size_t)NH * DOUT * DIN;        // 0.75 MB
    short* Fhi   = WloT + (size_t)NH * DOUT * DIN;        // 4 MB
    short* Flo   = Fhi  + (size_t)N_NODES * DIN;          // 4 MB

    // zero s_src | s_tgt | sums (contiguous)
    hipMemsetAsync(s_src, 0, (2 * NH * N_NODES + 2 * DOUT) * sizeof(float), stream);
    k1f_split<<<(size_t)N_NODES * DIN / 8 / 256, 256, 0, stream>>>(F, Fhi, Flo);
    k1w_split<<<dim3(DOUT / 64, DIN / 64, NH), 256, 0, stream>>>(W, WhiT, WloT);
    k1_proj<<<dim3(DOUT / 64, N_NODES / 128, NH), 256, 0, stream>>>(
        Fhi, Flo, WhiT, WloT, ssw, stw, proj, s_src, s_tgt);
    k3_attn<<<N_NODES / 4, 256, 0, stream>>>(A, proj, s_src, s_tgt, bias, out);
    k4_stats<<<N_NODES / 64, 256, 0, stream>>>(out, sums);
    k5_bn<<<(size_t)N_NODES * DOUT / 4 / 256, 256, 0, stream>>>(out, sums, gamma, beta);
}